// Round 1
// baseline (347.610 us; speedup 1.0000x reference)
//
#include <hip/hip_runtime.h>

typedef unsigned short u16;
typedef unsigned int   u32;

#define BATCH 4
#define SEQ   8192
#define DIM   1024
#define FL    2048
#define TROW  10240   // padded time row: covers k up to (8192-512)+2559 = 10239

// main kernel tiling
#define BM 512        // time rows per block
#define BN 64         // dims per block
#define BK 64         // staged K per stage
#define NSTAGE 40     // ceil((BM-1+FL)/BK) = 2559/64 -> 40
#define WOFF 64       // W[w][j] = filt[w - WOFF + j]
#define NW   2272     // windows: read range verified [2, 2262]
#define WIN_HI 2174   // last active kk rel to wave base: 7*16+15 + FL-1

typedef float  f32x4  __attribute__((ext_vector_type(4)));
typedef __bf16 bf16x8 __attribute__((ext_vector_type(8)));
typedef short  s16x8  __attribute__((ext_vector_type(8)));

typedef const __attribute__((address_space(1))) void* gas_t;
typedef __attribute__((address_space(3))) void* las_t;

__device__ __forceinline__ u16 f2bf(float f) {
  u32 u = __float_as_uint(f);
  u += 0x7fffu + ((u >> 16) & 1u);   // round-to-nearest-even
  return (u16)(u >> 16);
}

// ---- pass 1: x[b][t][d] fp32 -> xT[b][d][t] bf16, zero-padded for t in [SEQ, TROW)
__global__ __launch_bounds__(256) void k_transpose(const float* __restrict__ x,
                                                   u16* __restrict__ xT) {
  __shared__ __align__(16) u16 sm[64 * 66];   // [t][d], stride 66 breaks bank conflicts
  const int bid = blockIdx.x;
  const int tb = bid % (TROW / 64);
  const int db = (bid / (TROW / 64)) % (DIM / 64);
  const int b  = bid / ((TROW / 64) * (DIM / 64));
  const int t0 = tb * 64, d0 = db * 64;
  const int tid = threadIdx.x;

  // load: 16 threads x float4 cover one 64-wide d row; 16 t-rows per sweep
  const int c4 = tid & 15;
  const int lt = tid >> 4;
  const float* xb = x + (size_t)b * SEQ * DIM + d0 + c4 * 4;
  #pragma unroll
  for (int s = 0; s < 64; s += 16) {
    const int tl = lt + s;
    const int t = t0 + tl;
    float4 v = make_float4(0.f, 0.f, 0.f, 0.f);
    if (t < SEQ) v = *(const float4*)(xb + (size_t)t * DIM);
    u32 p0 = (u32)f2bf(v.x) | ((u32)f2bf(v.y) << 16);
    u32 p1 = (u32)f2bf(v.z) | ((u32)f2bf(v.w) << 16);
    u32* dst = (u32*)&sm[tl * 66 + c4 * 4];
    dst[0] = p0;
    dst[1] = p1;
  }
  __syncthreads();
  // store: lane pair-of-t (u32) along contiguous t, per d row
  const int tp = tid & 31;
  const int dl = tid >> 5;
  u16* xo = xT + ((size_t)b * DIM + d0) * TROW + t0 + 2 * tp;
  #pragma unroll
  for (int s = 0; s < 64; s += 8) {
    const int d = dl + s;
    u32 v = (u32)sm[(2 * tp) * 66 + d] | ((u32)sm[(2 * tp + 1) * 66 + d] << 16);
    *(u32*)(xo + (size_t)d * TROW) = v;
  }
}

// ---- pass 2: banded-Toeplitz MFMA conv.
// Out[t,d] = sum_k filt[k-t] * x[k,d].  A = Toeplitz (M=t), B = xT (N=d), K = k.
// Wave: 128(t) x 64(d) = 8 m-tiles x 4 n-tiles of 16x16x32 MFMA.
// Rolling A: A(mt)@step == A(mt-2)@(step-1)  -> only 2 A-frag LDS loads per 32 MFMAs.
__global__ __launch_bounds__(256, 2) void k_conv(const u16* __restrict__ xT,
                                                 const float* __restrict__ filt,
                                                 float* __restrict__ out) {
  __shared__ __align__(16) u16 Wb[NW * 8];    // filter windows, 35.5 KB
  __shared__ __align__(16) u16 Xs[BN * BK];   // staged x, 8 KB, chunk-swizzled

  const int bid = blockIdx.x;
  const int tb = bid & 15;
  const int db = (bid >> 4) & 15;
  const int b  = bid >> 8;
  const int t0 = tb * BM;
  const int d0 = db * BN;

  const int tid  = threadIdx.x;
  const int wid  = tid >> 6;
  const int lane = tid & 63;
  const int quad = lane >> 4;
  const int lq   = lane & 15;
  const int Tw   = wid * 128;   // wave's time base within block

  // build filter windows: Wb[w][j] = bf16(filt[w - WOFF + j]), zeros outside [0,FL)
  for (int w = tid; w < NW; w += 256) {
    const int base = w - WOFF;
    u32 pk[4];
    #pragma unroll
    for (int h = 0; h < 4; ++h) {
      const int i0 = base + 2 * h;
      const int i1 = i0 + 1;
      const float v0 = (i0 >= 0 && i0 < FL) ? filt[i0] : 0.f;
      const float v1 = (i1 >= 0 && i1 < FL) ? filt[i1] : 0.f;
      pk[h] = (u32)f2bf(v0) | ((u32)f2bf(v1) << 16);
    }
    u32* dst = (u32*)&Wb[w * 8];
    dst[0] = pk[0]; dst[1] = pk[1]; dst[2] = pk[2]; dst[3] = pk[3];
  }

  // staging decode: physical chunk p -> row d = p>>3, k-chunk kc = (p&7) ^ (d&7)
  // (XOR swizzle keeps B-frag ds_read_b128 conflict-free while matching
  //  global_load_lds's "base + lane*16" LDS placement)
  const u16* xrow = xT + ((size_t)b * DIM + d0) * TROW + t0;
  const int p0 = wid * 128 + lane;
  const int p1 = p0 + 64;
  const int ds0 = p0 >> 3, kc0 = (p0 & 7) ^ (ds0 & 7);
  const int ds1 = p1 >> 3, kc1 = (p1 & 7) ^ (ds1 & 7);
  const u16* gp0 = xrow + (size_t)ds0 * TROW + kc0 * 8;
  const u16* gp1 = xrow + (size_t)ds1 * TROW + kc1 * 8;
  u16* lds0 = &Xs[wid * 1024];   // wave-uniform base; lane lands at +lane*16B
  u16* lds1 = lds0 + 512;

  f32x4 acc[8][4];
  const f32x4 fz = {0.f, 0.f, 0.f, 0.f};
  #pragma unroll
  for (int i = 0; i < 8; ++i)
    #pragma unroll
    for (int j = 0; j < 4; ++j) acc[i][j] = fz;

  const s16x8 sz = {0, 0, 0, 0, 0, 0, 0, 0};
  bf16x8 roll0 = __builtin_bit_cast(bf16x8, sz);
  bf16x8 roll1 = roll0, roll2 = roll0, roll3 = roll0, roll4 = roll0, roll5 = roll0;

  const int wconst = quad * 8 - Tw - lq + WOFF;
  const int kkLo = Tw - 31;        // active: kk+31 >= Tw
  const int kkHi = Tw + WIN_HI;    // active: kk <= Tw + 2174

  for (int st = 0; st < NSTAGE; ++st) {
    const int kk0 = st * BK;
    __syncthreads();
    __builtin_amdgcn_global_load_lds((gas_t)(gp0 + kk0), (las_t)lds0, 16, 0, 0);
    __builtin_amdgcn_global_load_lds((gas_t)(gp1 + kk0), (las_t)lds1, 16, 0, 0);
    __syncthreads();
    #pragma unroll
    for (int half = 0; half < 2; ++half) {
      const int kk = kk0 + half * 32;
      if (kk >= kkLo && kk <= kkHi) {
        bf16x8 bfr[4];
        #pragma unroll
        for (int nt = 0; nt < 4; ++nt) {
          const int dl = nt * 16 + lq;
          const int kc = (half * 4 + quad) ^ (dl & 7);
          bfr[nt] = *(const bf16x8*)&Xs[(dl * 8 + kc) * 8];
        }
        const int w0 = kk + wconst;
        const bf16x8 a0 = *(const bf16x8*)&Wb[w0 * 8];
        const bf16x8 a1 = *(const bf16x8*)&Wb[(w0 - 16) * 8];
        #pragma unroll
        for (int nt = 0; nt < 4; ++nt) {
          acc[0][nt] = __builtin_amdgcn_mfma_f32_16x16x32_bf16(a0,    bfr[nt], acc[0][nt], 0, 0, 0);
          acc[1][nt] = __builtin_amdgcn_mfma_f32_16x16x32_bf16(a1,    bfr[nt], acc[1][nt], 0, 0, 0);
          acc[2][nt] = __builtin_amdgcn_mfma_f32_16x16x32_bf16(roll0, bfr[nt], acc[2][nt], 0, 0, 0);
          acc[3][nt] = __builtin_amdgcn_mfma_f32_16x16x32_bf16(roll1, bfr[nt], acc[3][nt], 0, 0, 0);
          acc[4][nt] = __builtin_amdgcn_mfma_f32_16x16x32_bf16(roll2, bfr[nt], acc[4][nt], 0, 0, 0);
          acc[5][nt] = __builtin_amdgcn_mfma_f32_16x16x32_bf16(roll3, bfr[nt], acc[5][nt], 0, 0, 0);
          acc[6][nt] = __builtin_amdgcn_mfma_f32_16x16x32_bf16(roll4, bfr[nt], acc[6][nt], 0, 0, 0);
          acc[7][nt] = __builtin_amdgcn_mfma_f32_16x16x32_bf16(roll5, bfr[nt], acc[7][nt], 0, 0, 0);
        }
        roll5 = roll3; roll4 = roll2; roll3 = roll1; roll2 = roll0;
        roll1 = a1; roll0 = a0;
      }
    }
  }

  // epilogue: C/D layout col = lane&15 (d), row = quad*4 + reg (t)
  float* ob = out + ((size_t)b * SEQ + t0 + Tw) * DIM + d0;
  #pragma unroll
  for (int mt = 0; mt < 8; ++mt) {
    #pragma unroll
    for (int nt = 0; nt < 4; ++nt) {
      #pragma unroll
      for (int r = 0; r < 4; ++r) {
        ob[(size_t)(mt * 16 + quad * 4 + r) * DIM + nt * 16 + lq] = acc[mt][nt][r];
      }
    }
  }
}

extern "C" void kernel_launch(void* const* d_in, const int* in_sizes, int n_in,
                              void* d_out, int out_size, void* d_ws, size_t ws_size,
                              hipStream_t stream) {
  const float* x    = (const float*)d_in[0];
  const float* filt = (const float*)d_in[1];
  float* out = (float*)d_out;
  u16* xT = (u16*)d_ws;   // needs 4*1024*10240*2 = 83.9 MB of workspace
  (void)in_sizes; (void)n_in; (void)out_size; (void)ws_size;

  k_transpose<<<BATCH * (TROW / 64) * (DIM / 64), 256, 0, stream>>>(x, xT);
  k_conv<<<BATCH * 16 * 16, 256, 0, stream>>>(xT, filt, out);
}

// Round 2
// 345.006 us; speedup vs baseline: 1.0075x; 1.0075x over previous
//
#include <hip/hip_runtime.h>

typedef unsigned short u16;
typedef unsigned int   u32;

#define BATCH 4
#define SEQ   8192
#define DIM   1024
#define FL    2048
#define TROW  10240   // padded time row: covers k up to (8192-512)+2559 = 10239

// main kernel tiling
#define BM 512        // time rows per block
#define BN 64         // dims per block
#define BK 64         // staged K per stage
#define NSTAGE 40     // ceil((BM-1+FL)/BK) = 2559/64 -> 40
#define WOFF 64       // W[w][j] = filt[w - WOFF + j]
#define NW   2272     // windows: read range verified [2, 2262]
#define WIN_HI 2174   // last active kk rel to wave base: 7*16+15 + FL-1

typedef float  f32x4  __attribute__((ext_vector_type(4)));
typedef __bf16 bf16x8 __attribute__((ext_vector_type(8)));
typedef short  s16x8  __attribute__((ext_vector_type(8)));

typedef const __attribute__((address_space(1))) void* gas_t;
typedef __attribute__((address_space(3))) void* las_t;

__device__ __forceinline__ u16 f2bf(float f) {
  u32 u = __float_as_uint(f);
  u += 0x7fffu + ((u >> 16) & 1u);   // round-to-nearest-even
  return (u16)(u >> 16);
}

// ---- pass 1: x[b][t][d] fp32 -> xT[b][d][t] bf16, zero-padded for t in [SEQ, TROW)
__global__ __launch_bounds__(256) void k_transpose(const float* __restrict__ x,
                                                   u16* __restrict__ xT) {
  __shared__ __align__(16) u16 sm[64 * 66];   // [t][d], stride 66 breaks bank conflicts
  const int bid = blockIdx.x;
  const int tb = bid % (TROW / 64);
  const int db = (bid / (TROW / 64)) % (DIM / 64);
  const int b  = bid / ((TROW / 64) * (DIM / 64));
  const int t0 = tb * 64, d0 = db * 64;
  const int tid = threadIdx.x;

  // load: 16 threads x float4 cover one 64-wide d row; 16 t-rows per sweep
  const int c4 = tid & 15;
  const int lt = tid >> 4;
  const float* xb = x + (size_t)b * SEQ * DIM + d0 + c4 * 4;
  #pragma unroll
  for (int s = 0; s < 64; s += 16) {
    const int tl = lt + s;
    const int t = t0 + tl;
    float4 v = make_float4(0.f, 0.f, 0.f, 0.f);
    if (t < SEQ) v = *(const float4*)(xb + (size_t)t * DIM);
    u32 p0 = (u32)f2bf(v.x) | ((u32)f2bf(v.y) << 16);
    u32 p1 = (u32)f2bf(v.z) | ((u32)f2bf(v.w) << 16);
    u32* dst = (u32*)&sm[tl * 66 + c4 * 4];
    dst[0] = p0;
    dst[1] = p1;
  }
  __syncthreads();
  // store: lane packs 8 consecutive t (16 B) per d row -> dwordx4 stores.
  // 8 lanes cover the 64-t extent (128 B contiguous per row); 8 rows per wave instr.
  const int q  = tid & 7;
  const int dl = tid >> 3;   // 0..31
  u16* xo = xT + ((size_t)b * DIM + d0) * TROW + t0 + 8 * q;
  #pragma unroll
  for (int s = 0; s < 2; ++s) {
    const int d = dl + 32 * s;
    u32 w[4];
    #pragma unroll
    for (int h = 0; h < 4; ++h) {
      w[h] = (u32)sm[(8 * q + 2 * h) * 66 + d] |
             ((u32)sm[(8 * q + 2 * h + 1) * 66 + d] << 16);
    }
    *(uint4*)(xo + (size_t)d * TROW) = *(const uint4*)w;
  }
}

// ---- pass 2: banded-Toeplitz MFMA conv.
// Out[t,d] = sum_k filt[k-t] * x[k,d].  A = Toeplitz (M=t), B = xT (N=d), K = k.
// Wave: 128(t) x 64(d) = 8 m-tiles x 4 n-tiles of 16x16x32 MFMA.
// Rolling A: A(mt)@step == A(mt-2)@(step-1)  -> only 2 A-frag LDS loads per 32 MFMAs.
// Single-barrier double-buffered staging: prefetch st+1 right after the barrier,
// compute st; the compiler's vmcnt(0)-before-s_barrier then drains AFTER ~600cyc
// of MFMA instead of immediately (latency hidden).
__global__ __launch_bounds__(256, 2) void k_conv(const u16* __restrict__ xT,
                                                 const float* __restrict__ filt,
                                                 float* __restrict__ out) {
  __shared__ __align__(16) u16 Wb[NW * 8];       // filter windows, 35.5 KB
  __shared__ __align__(16) u16 Xs[2][BN * BK];   // staged x, 2 x 8 KB, chunk-swizzled

  const int bid = blockIdx.x;
  const int tb = bid & 15;
  const int db = (bid >> 4) & 15;
  const int b  = bid >> 8;
  const int t0 = tb * BM;
  const int d0 = db * BN;

  const int tid  = threadIdx.x;
  const int wid  = tid >> 6;
  const int lane = tid & 63;
  const int quad = lane >> 4;
  const int lq   = lane & 15;
  const int Tw   = wid * 128;   // wave's time base within block

  // build filter windows: Wb[w][j] = bf16(filt[w - WOFF + j]), zeros outside [0,FL)
  for (int w = tid; w < NW; w += 256) {
    const int base = w - WOFF;
    u32 pk[4];
    #pragma unroll
    for (int h = 0; h < 4; ++h) {
      const int i0 = base + 2 * h;
      const int i1 = i0 + 1;
      const float v0 = (i0 >= 0 && i0 < FL) ? filt[i0] : 0.f;
      const float v1 = (i1 >= 0 && i1 < FL) ? filt[i1] : 0.f;
      pk[h] = (u32)f2bf(v0) | ((u32)f2bf(v1) << 16);
    }
    u32* dst = (u32*)&Wb[w * 8];
    dst[0] = pk[0]; dst[1] = pk[1]; dst[2] = pk[2]; dst[3] = pk[3];
  }

  // staging decode: physical chunk p -> row d = p>>3, k-chunk kc = (p&7) ^ (d&7)
  // (XOR swizzle keeps B-frag ds_read_b128 conflict-free while matching
  //  global_load_lds's "base + lane*16" LDS placement)
  const u16* xrow = xT + ((size_t)b * DIM + d0) * TROW + t0;
  const int p0 = wid * 128 + lane;
  const int p1 = p0 + 64;
  const int ds0 = p0 >> 3, kc0 = (p0 & 7) ^ (ds0 & 7);
  const int ds1 = p1 >> 3, kc1 = (p1 & 7) ^ (ds1 & 7);
  const u16* gp0 = xrow + (size_t)ds0 * TROW + kc0 * 8;
  const u16* gp1 = xrow + (size_t)ds1 * TROW + kc1 * 8;

  f32x4 acc[8][4];
  const f32x4 fz = {0.f, 0.f, 0.f, 0.f};
  #pragma unroll
  for (int i = 0; i < 8; ++i)
    #pragma unroll
    for (int j = 0; j < 4; ++j) acc[i][j] = fz;

  const s16x8 sz = {0, 0, 0, 0, 0, 0, 0, 0};
  bf16x8 roll0 = __builtin_bit_cast(bf16x8, sz);
  bf16x8 roll1 = roll0, roll2 = roll0, roll3 = roll0, roll4 = roll0, roll5 = roll0;

  const int wconst = quad * 8 - Tw - lq + WOFF;
  const int kkLo = Tw - 31;        // active: kk+31 >= Tw
  const int kkHi = Tw + WIN_HI;    // active: kk <= Tw + 2174

  // prefetch stage 0 into buffer 0
  {
    u16* nb = &Xs[0][wid * 1024];
    __builtin_amdgcn_global_load_lds((gas_t)gp0, (las_t)nb, 16, 0, 0);
    __builtin_amdgcn_global_load_lds((gas_t)gp1, (las_t)(nb + 512), 16, 0, 0);
  }

  for (int st = 0; st < NSTAGE; ++st) {
    // drains prefetch(st) [vmcnt(0) emitted before s_barrier] and, on st=0,
    // the Wb LDS stores [lgkmcnt(0)].
    __syncthreads();
    if (st + 1 < NSTAGE) {   // block-uniform branch
      const int kkn = (st + 1) * BK;
      u16* nb = &Xs[(st + 1) & 1][wid * 1024];
      __builtin_amdgcn_global_load_lds((gas_t)(gp0 + kkn), (las_t)nb, 16, 0, 0);
      __builtin_amdgcn_global_load_lds((gas_t)(gp1 + kkn), (las_t)(nb + 512), 16, 0, 0);
    }
    const u16* Xc = &Xs[st & 1][0];
    const int kk0 = st * BK;
    #pragma unroll
    for (int half = 0; half < 2; ++half) {
      const int kk = kk0 + half * 32;
      if (kk >= kkLo && kk <= kkHi) {
        bf16x8 bfr[4];
        #pragma unroll
        for (int nt = 0; nt < 4; ++nt) {
          const int dl = nt * 16 + lq;
          const int kc = (half * 4 + quad) ^ (dl & 7);
          bfr[nt] = *(const bf16x8*)&Xc[(dl * 8 + kc) * 8];
        }
        const int w0 = kk + wconst;
        const bf16x8 a0 = *(const bf16x8*)&Wb[w0 * 8];
        const bf16x8 a1 = *(const bf16x8*)&Wb[(w0 - 16) * 8];
        #pragma unroll
        for (int nt = 0; nt < 4; ++nt) {
          acc[0][nt] = __builtin_amdgcn_mfma_f32_16x16x32_bf16(a0,    bfr[nt], acc[0][nt], 0, 0, 0);
          acc[1][nt] = __builtin_amdgcn_mfma_f32_16x16x32_bf16(a1,    bfr[nt], acc[1][nt], 0, 0, 0);
          acc[2][nt] = __builtin_amdgcn_mfma_f32_16x16x32_bf16(roll0, bfr[nt], acc[2][nt], 0, 0, 0);
          acc[3][nt] = __builtin_amdgcn_mfma_f32_16x16x32_bf16(roll1, bfr[nt], acc[3][nt], 0, 0, 0);
          acc[4][nt] = __builtin_amdgcn_mfma_f32_16x16x32_bf16(roll2, bfr[nt], acc[4][nt], 0, 0, 0);
          acc[5][nt] = __builtin_amdgcn_mfma_f32_16x16x32_bf16(roll3, bfr[nt], acc[5][nt], 0, 0, 0);
          acc[6][nt] = __builtin_amdgcn_mfma_f32_16x16x32_bf16(roll4, bfr[nt], acc[6][nt], 0, 0, 0);
          acc[7][nt] = __builtin_amdgcn_mfma_f32_16x16x32_bf16(roll5, bfr[nt], acc[7][nt], 0, 0, 0);
        }
        roll5 = roll3; roll4 = roll2; roll3 = roll1; roll2 = roll0;
        roll1 = a1; roll0 = a0;
      }
    }
  }

  // epilogue: C/D layout col = lane&15 (d), row = quad*4 + reg (t)
  float* ob = out + ((size_t)b * SEQ + t0 + Tw) * DIM + d0;
  #pragma unroll
  for (int mt = 0; mt < 8; ++mt) {
    #pragma unroll
    for (int nt = 0; nt < 4; ++nt) {
      #pragma unroll
      for (int r = 0; r < 4; ++r) {
        ob[(size_t)(mt * 16 + quad * 4 + r) * DIM + nt * 16 + lq] = acc[mt][nt][r];
      }
    }
  }
}

extern "C" void kernel_launch(void* const* d_in, const int* in_sizes, int n_in,
                              void* d_out, int out_size, void* d_ws, size_t ws_size,
                              hipStream_t stream) {
  const float* x    = (const float*)d_in[0];
  const float* filt = (const float*)d_in[1];
  float* out = (float*)d_out;
  u16* xT = (u16*)d_ws;   // needs 4*1024*10240*2 = 83.9 MB of workspace
  (void)in_sizes; (void)n_in; (void)out_size; (void)ws_size;

  k_transpose<<<BATCH * (TROW / 64) * (DIM / 64), 256, 0, stream>>>(x, xT);
  k_conv<<<BATCH * 16 * 16, 256, 0, stream>>>(xT, filt, out);
}